// Round 1
// baseline (2906.874 us; speedup 1.0000x reference)
//
#include <hip/hip_runtime.h>

// ---------------------------------------------------------------------------
// Direct VALID conv (used for the offset-producing convs).
// Each thread: one spatial output position, NOC consecutive output channels.
// Weight addresses are block-uniform -> scalar loads; input loads coalesced.
// ---------------------------------------------------------------------------
template<int K, int CI, int NOC, int OC, int H, int W, int Ho, int Wo>
__global__ __launch_bounds__(256)
void conv_direct(const float* __restrict__ x, const float* __restrict__ w,
                 const float* __restrict__ bias, float* __restrict__ out)
{
    constexpr int HoWo = Ho * Wo;
    const int b   = blockIdx.z;
    const int oc0 = blockIdx.y * NOC;
    const int s   = blockIdx.x * 256 + threadIdx.x;
    if (s >= HoWo) return;
    const int oy = s / Wo;
    const int ox = s - oy * Wo;

    const float* xb = x + (b * CI) * (H * W) + oy * W + ox;
    const float* wp = w + oc0 * (CI * K * K);

    float acc[NOC];
#pragma unroll
    for (int j = 0; j < NOC; ++j) acc[j] = bias[oc0 + j];

    for (int ci = 0; ci < CI; ++ci) {
        const float* xc = xb + ci * (H * W);
        const float* wc = wp + ci * (K * K);
#pragma unroll
        for (int ky = 0; ky < K; ++ky) {
#pragma unroll
            for (int kx = 0; kx < K; ++kx) {
                const float v = xc[ky * W + kx];
#pragma unroll
                for (int j = 0; j < NOC; ++j)
                    acc[j] = fmaf(v, wc[j * (CI * K * K) + ky * K + kx], acc[j]);
            }
        }
    }

    float* op = out + (b * OC + oc0) * HoWo + s;
#pragma unroll
    for (int j = 0; j < NOC; ++j) op[j * HoWo] = acc[j];
}

// ---------------------------------------------------------------------------
// Deformable conv. Each thread: one output pixel, all CO output channels.
// Per kernel tap kk: read the 2 offsets, build 4 bilinear corner weights with
// per-corner validity (matches reference exactly), then for each input channel
// gather 4 corners, form the sample, and FMA into all CO accumulators.
// ---------------------------------------------------------------------------
template<int K, int CI, int CO, int H, int W, int Ho, int Wo, bool RELU>
__global__ __launch_bounds__(256)
void deform_conv(const float* __restrict__ x, const float* __restrict__ off,
                 const float* __restrict__ w, const float* __restrict__ bias,
                 float* __restrict__ out)
{
    constexpr int KK   = K * K;
    constexpr int HoWo = Ho * Wo;
    const int b = blockIdx.y;
    const int s = blockIdx.x * 256 + threadIdx.x;
    if (s >= HoWo) return;
    const int oy = s / Wo;
    const int ox = s - oy * Wo;

    const float* xb   = x + b * (CI * H * W);
    const float* offp = off + (b * 2 * KK) * HoWo + s;

    float acc[CO];
#pragma unroll
    for (int o = 0; o < CO; ++o) acc[o] = 0.f;

    for (int kk = 0; kk < KK; ++kk) {
        const float dy = offp[(2 * kk + 0) * HoWo];
        const float dx = offp[(2 * kk + 1) * HoWo];
        const float py = (float)(kk / K + oy) + dy;
        const float px = (float)(kk % K + ox) + dx;
        const float y0f = floorf(py), x0f = floorf(px);
        const float wy = py - y0f, wx = px - x0f;
        const int y0 = (int)y0f, x0 = (int)x0f;
        const int y1 = y0 + 1,   x1 = x0 + 1;

        const float m00 = (y0 >= 0 && y0 < H && x0 >= 0 && x0 < W) ? 1.f : 0.f;
        const float m01 = (y0 >= 0 && y0 < H && x1 >= 0 && x1 < W) ? 1.f : 0.f;
        const float m10 = (y1 >= 0 && y1 < H && x0 >= 0 && x0 < W) ? 1.f : 0.f;
        const float m11 = (y1 >= 0 && y1 < H && x1 >= 0 && x1 < W) ? 1.f : 0.f;

        const float w00 = (1.f - wy) * (1.f - wx) * m00;
        const float w01 = (1.f - wy) * wx         * m01;
        const float w10 = wy         * (1.f - wx) * m10;
        const float w11 = wy         * wx         * m11;

        const int y0c = min(max(y0, 0), H - 1), y1c = min(max(y1, 0), H - 1);
        const int x0c = min(max(x0, 0), W - 1), x1c = min(max(x1, 0), W - 1);
        const int i00 = y0c * W + x0c, i01 = y0c * W + x1c;
        const int i10 = y1c * W + x0c, i11 = y1c * W + x1c;

        for (int c = 0; c < CI; ++c) {
            const float* xc = xb + c * (H * W);
            float sv = xc[i00] * w00;
            sv = fmaf(xc[i01], w01, sv);
            sv = fmaf(xc[i10], w10, sv);
            sv = fmaf(xc[i11], w11, sv);
#pragma unroll
            for (int o = 0; o < CO; ++o)
                acc[o] = fmaf(sv, w[(o * CI + c) * KK + kk], acc[o]);
        }
    }

    float* op = out + (b * CO) * HoWo + s;
#pragma unroll
    for (int o = 0; o < CO; ++o) {
        float v = acc[o] + bias[o];
        if (RELU) v = fmaxf(v, 0.f);
        op[o * HoWo] = v;
    }
}

// ---------------------------------------------------------------------------
// Fully-connected: out[b,j] = (relu?) dot(h[b,:], w[j,:]) + bias[j]
// ---------------------------------------------------------------------------
__global__ void fc_kernel(const float* __restrict__ h, const float* __restrict__ w,
                          const float* __restrict__ bias, float* __restrict__ out,
                          int B, int IN, int OUT, int relu)
{
    const int idx = blockIdx.x * blockDim.x + threadIdx.x;
    if (idx >= B * OUT) return;
    const int b = idx / OUT;
    const int j = idx - b * OUT;
    const float* hb = h + b * IN;
    const float* wj = w + j * IN;
    float acc = bias[j];
    for (int i = 0; i < IN; ++i) acc = fmaf(hb[i], wj[i], acc);
    if (relu) acc = fmaxf(acc, 0.f);
    out[idx] = acc;
}

// ---------------------------------------------------------------------------
// Stage plan (B=512):
//  1: CI= 1 CO=16 K=3  33x33 -> 31x31  OCoff=18  relu
//  2: CI=16 CO=32 K=3  31x31 -> 29x29  OCoff=18  relu
//  3: CI=32 CO=16 K=5  29x29 -> 25x25  OCoff=50  (no relu)
//  4: CI=16 CO=16 K=7  25x25 -> 19x19  OCoff=98  relu
//  5: CI=16 CO= 8 K=5  19x19 -> 15x15  OCoff=50  relu
//  6: CI= 8 CO= 4 K=3  15x15 -> 13x13  OCoff=18  relu
//  fc1: 676->256 relu, fc2: 256->10
// ---------------------------------------------------------------------------
extern "C" void kernel_launch(void* const* d_in, const int* in_sizes, int n_in,
                              void* d_out, int out_size, void* d_ws, size_t ws_size,
                              hipStream_t stream)
{
    const int B = 512;
    const float* x = (const float*)d_in[0];
    const float *ow[6], *ob[6], *w[6], *bi[6];
    for (int i = 0; i < 6; ++i) {
        ow[i] = (const float*)d_in[1 + 4 * i];
        ob[i] = (const float*)d_in[2 + 4 * i];
        w[i]  = (const float*)d_in[3 + 4 * i];
        bi[i] = (const float*)d_in[4 + 4 * i];
    }
    const float* fc1w = (const float*)d_in[25];
    const float* fc1b = (const float*)d_in[26];
    const float* fc2w = (const float*)d_in[27];
    const float* fc2b = (const float*)d_in[28];
    float* out = (float*)d_out;

    // workspace layout (floats): A | Bb | OFF | Z
    float* A   = (float*)d_ws;
    float* Bb  = A  + 14000000;   // max activation = 512*32*29*29 = 13,778,944
    float* OFF = Bb + 14000000;
    float* Z   = OFF + 18200000;  // max offsets   = 512*98*19*19 = 18,119,936

    const dim3 blk(256);
    #define GRIDC(HoWo, NG) dim3(((HoWo) + 255) / 256, (NG), B)
    #define GRIDD(HoWo)     dim3(((HoWo) + 255) / 256, B)

    // stage 1
    conv_direct<3, 1, 6, 18, 33, 33, 31, 31><<<GRIDC(961, 3), blk, 0, stream>>>(x, ow[0], ob[0], OFF);
    deform_conv<3, 1, 16, 33, 33, 31, 31, true><<<GRIDD(961), blk, 0, stream>>>(x, OFF, w[0], bi[0], A);
    // stage 2
    conv_direct<3, 16, 6, 18, 31, 31, 29, 29><<<GRIDC(841, 3), blk, 0, stream>>>(A, ow[1], ob[1], OFF);
    deform_conv<3, 16, 32, 31, 31, 29, 29, true><<<GRIDD(841), blk, 0, stream>>>(A, OFF, w[1], bi[1], Bb);
    // stage 3 (no relu)
    conv_direct<5, 32, 10, 50, 29, 29, 25, 25><<<GRIDC(625, 5), blk, 0, stream>>>(Bb, ow[2], ob[2], OFF);
    deform_conv<5, 32, 16, 29, 29, 25, 25, false><<<GRIDD(625), blk, 0, stream>>>(Bb, OFF, w[2], bi[2], A);
    // stage 4
    conv_direct<7, 16, 14, 98, 25, 25, 19, 19><<<GRIDC(361, 7), blk, 0, stream>>>(A, ow[3], ob[3], OFF);
    deform_conv<7, 16, 16, 25, 25, 19, 19, true><<<GRIDD(361), blk, 0, stream>>>(A, OFF, w[3], bi[3], Bb);
    // stage 5
    conv_direct<5, 16, 10, 50, 19, 19, 15, 15><<<GRIDC(225, 5), blk, 0, stream>>>(Bb, ow[4], ob[4], OFF);
    deform_conv<5, 16, 8, 19, 19, 15, 15, true><<<GRIDD(225), blk, 0, stream>>>(Bb, OFF, w[4], bi[4], A);
    // stage 6
    conv_direct<3, 8, 6, 18, 15, 15, 13, 13><<<GRIDC(169, 3), blk, 0, stream>>>(A, ow[5], ob[5], OFF);
    deform_conv<3, 8, 4, 15, 15, 13, 13, true><<<GRIDD(169), blk, 0, stream>>>(A, OFF, w[5], bi[5], Bb);

    // fc1: (512,676) -> (512,256), relu
    fc_kernel<<<dim3((B * 256 + 255) / 256), blk, 0, stream>>>(Bb, fc1w, fc1b, Z, B, 676, 256, 1);
    // fc2: (512,256) -> (512,10)
    fc_kernel<<<dim3((B * 10 + 255) / 256), blk, 0, stream>>>(Z, fc2w, fc2b, out, B, 256, 10, 0);

    #undef GRIDC
    #undef GRIDD
}

// Round 2
// 2849.715 us; speedup vs baseline: 1.0201x; 1.0201x over previous
//
#include <hip/hip_runtime.h>

// ---------------------------------------------------------------------------
// Register-tiled direct VALID conv (offset-producing convs).
// Each thread: PIX consecutive x-positions in one row × NOC output channels.
// Per (ci,ky): load PIX+K-1 row values once -> K*PIX*NOC FMAs.
// Weight/bias addresses are block-uniform -> scalar loads (off the VALU pipe).
// ---------------------------------------------------------------------------
template<int K, int CI, int NOC, int OC, int H, int W, int Ho, int Wo, int PIX>
__global__ __launch_bounds__(256)
void conv_tile(const float* __restrict__ x, const float* __restrict__ w,
               const float* __restrict__ bias, float* __restrict__ out)
{
    constexpr int KK   = K * K;
    constexpr int HoWo = Ho * Wo;
    constexpr int WoG  = (Wo + PIX - 1) / PIX;   // pixel-groups per row
    constexpr int G    = Ho * WoG;               // thread slots per image
    constexpr int XV   = PIX + K - 1;            // row values needed per thread

    const int oc0   = blockIdx.y * NOC;
    const int g_all = blockIdx.x * 256 + threadIdx.x;
    const int b     = g_all / G;
    if (b >= gridDim.z) {}                       // (unused; b bounded by grid calc)
    const int g     = g_all - b * G;
    const int oy    = g / WoG;
    const int ox0   = (g - oy * WoG) * PIX;

    const float* xb = x + (b * CI) * (H * W) + oy * W + ox0;
    const float* wp = w + oc0 * (CI * KK);

    float acc[PIX][NOC];
#pragma unroll
    for (int p = 0; p < PIX; ++p)
#pragma unroll
        for (int j = 0; j < NOC; ++j) acc[p][j] = bias[oc0 + j];

    const int lim = W - 1 - ox0;                 // max valid row offset

    for (int ci = 0; ci < CI; ++ci) {
        const float* xc = xb + ci * (H * W);
#pragma unroll
        for (int ky = 0; ky < K; ++ky) {
            float xv[XV];
#pragma unroll
            for (int i = 0; i < XV; ++i) {
                const int off = (i <= lim) ? i : lim;   // clamp (last group only)
                xv[i] = xc[ky * W + off];
            }
#pragma unroll
            for (int kx = 0; kx < K; ++kx) {
#pragma unroll
                for (int p = 0; p < PIX; ++p) {
                    const float v = xv[p + kx];
#pragma unroll
                    for (int j = 0; j < NOC; ++j)
                        acc[p][j] = fmaf(v, wp[j * (CI * KK) + ci * KK + ky * K + kx], acc[p][j]);
                }
            }
        }
    }

    float* op = out + (b * OC + oc0) * HoWo + oy * Wo + ox0;
#pragma unroll
    for (int p = 0; p < PIX; ++p) {
        if (ox0 + p < Wo) {
#pragma unroll
            for (int j = 0; j < NOC; ++j) op[j * HoWo + p] = acc[p][j];
        }
    }
}

// ---------------------------------------------------------------------------
// Deformable conv. Each thread: one output pixel, all CO output channels.
// ---------------------------------------------------------------------------
template<int K, int CI, int CO, int H, int W, int Ho, int Wo, bool RELU>
__global__ __launch_bounds__(256)
void deform_conv(const float* __restrict__ x, const float* __restrict__ off,
                 const float* __restrict__ w, const float* __restrict__ bias,
                 float* __restrict__ out)
{
    constexpr int KK   = K * K;
    constexpr int HoWo = Ho * Wo;
    const int b = blockIdx.y;
    const int s = blockIdx.x * 256 + threadIdx.x;
    if (s >= HoWo) return;
    const int oy = s / Wo;
    const int ox = s - oy * Wo;

    const float* xb   = x + b * (CI * H * W);
    const float* offp = off + (b * 2 * KK) * HoWo + s;

    float acc[CO];
#pragma unroll
    for (int o = 0; o < CO; ++o) acc[o] = 0.f;

    for (int kk = 0; kk < KK; ++kk) {
        const float dy = offp[(2 * kk + 0) * HoWo];
        const float dx = offp[(2 * kk + 1) * HoWo];
        const float py = (float)(kk / K + oy) + dy;
        const float px = (float)(kk % K + ox) + dx;
        const float y0f = floorf(py), x0f = floorf(px);
        const float wy = py - y0f, wx = px - x0f;
        const int y0 = (int)y0f, x0 = (int)x0f;
        const int y1 = y0 + 1,   x1 = x0 + 1;

        const float m00 = (y0 >= 0 && y0 < H && x0 >= 0 && x0 < W) ? 1.f : 0.f;
        const float m01 = (y0 >= 0 && y0 < H && x1 >= 0 && x1 < W) ? 1.f : 0.f;
        const float m10 = (y1 >= 0 && y1 < H && x0 >= 0 && x0 < W) ? 1.f : 0.f;
        const float m11 = (y1 >= 0 && y1 < H && x1 >= 0 && x1 < W) ? 1.f : 0.f;

        const float w00 = (1.f - wy) * (1.f - wx) * m00;
        const float w01 = (1.f - wy) * wx         * m01;
        const float w10 = wy         * (1.f - wx) * m10;
        const float w11 = wy         * wx         * m11;

        const int y0c = min(max(y0, 0), H - 1), y1c = min(max(y1, 0), H - 1);
        const int x0c = min(max(x0, 0), W - 1), x1c = min(max(x1, 0), W - 1);
        const int i00 = y0c * W + x0c, i01 = y0c * W + x1c;
        const int i10 = y1c * W + x0c, i11 = y1c * W + x1c;

        for (int c = 0; c < CI; ++c) {
            const float* xc = xb + c * (H * W);
            float sv = xc[i00] * w00;
            sv = fmaf(xc[i01], w01, sv);
            sv = fmaf(xc[i10], w10, sv);
            sv = fmaf(xc[i11], w11, sv);
#pragma unroll
            for (int o = 0; o < CO; ++o)
                acc[o] = fmaf(sv, w[(o * CI + c) * KK + kk], acc[o]);
        }
    }

    float* op = out + (b * CO) * HoWo + s;
#pragma unroll
    for (int o = 0; o < CO; ++o) {
        float v = acc[o] + bias[o];
        if (RELU) v = fmaxf(v, 0.f);
        op[o * HoWo] = v;
    }
}

// ---------------------------------------------------------------------------
// Fully-connected: out[b,j] = (relu?) dot(h[b,:], w[j,:]) + bias[j]
// ---------------------------------------------------------------------------
__global__ void fc_kernel(const float* __restrict__ h, const float* __restrict__ w,
                          const float* __restrict__ bias, float* __restrict__ out,
                          int B, int IN, int OUT, int relu)
{
    const int idx = blockIdx.x * blockDim.x + threadIdx.x;
    if (idx >= B * OUT) return;
    const int b = idx / OUT;
    const int j = idx - b * OUT;
    const float* hb = h + b * IN;
    const float* wj = w + j * IN;
    float acc = bias[j];
    for (int i = 0; i < IN; ++i) acc = fmaf(hb[i], wj[i], acc);
    if (relu) acc = fmaxf(acc, 0.f);
    out[idx] = acc;
}

// ---------------------------------------------------------------------------
// Stage plan (B=512):
//  1: CI= 1 CO=16 K=3  33x33 -> 31x31  OCoff=18  relu
//  2: CI=16 CO=32 K=3  31x31 -> 29x29  OCoff=18  relu
//  3: CI=32 CO=16 K=5  29x29 -> 25x25  OCoff=50  (no relu)
//  4: CI=16 CO=16 K=7  25x25 -> 19x19  OCoff=98  relu
//  5: CI=16 CO= 8 K=5  19x19 -> 15x15  OCoff=50  relu
//  6: CI= 8 CO= 4 K=3  15x15 -> 13x13  OCoff=18  relu
// ---------------------------------------------------------------------------
extern "C" void kernel_launch(void* const* d_in, const int* in_sizes, int n_in,
                              void* d_out, int out_size, void* d_ws, size_t ws_size,
                              hipStream_t stream)
{
    const int B = 512;
    const float* x = (const float*)d_in[0];
    const float *ow[6], *ob[6], *w[6], *bi[6];
    for (int i = 0; i < 6; ++i) {
        ow[i] = (const float*)d_in[1 + 4 * i];
        ob[i] = (const float*)d_in[2 + 4 * i];
        w[i]  = (const float*)d_in[3 + 4 * i];
        bi[i] = (const float*)d_in[4 + 4 * i];
    }
    const float* fc1w = (const float*)d_in[25];
    const float* fc1b = (const float*)d_in[26];
    const float* fc2w = (const float*)d_in[27];
    const float* fc2b = (const float*)d_in[28];
    float* out = (float*)d_out;

    // workspace layout (floats): A | Bb | OFF | Z
    float* A   = (float*)d_ws;
    float* Bb  = A  + 14000000;   // max activation = 512*32*29*29 = 13,778,944
    float* OFF = Bb + 14000000;
    float* Z   = OFF + 18200000;  // max offsets   = 512*98*19*19 = 18,119,936

    const dim3 blk(256);

    // grid helper for conv_tile: total threads = B * Ho * ceil(Wo/PIX)
    #define GRIDT(Ho, Wo, PIX, NG) dim3((B * (Ho) * (((Wo) + (PIX) - 1) / (PIX)) + 255) / 256, (NG), 1)
    #define GRIDD(HoWo)            dim3(((HoWo) + 255) / 256, B)

    // stage 1
    conv_tile<3, 1, 6, 18, 33, 33, 31, 31, 4><<<GRIDT(31, 31, 4, 3), blk, 0, stream>>>(x, ow[0], ob[0], OFF);
    deform_conv<3, 1, 16, 33, 33, 31, 31, true><<<GRIDD(961), blk, 0, stream>>>(x, OFF, w[0], bi[0], A);
    // stage 2
    conv_tile<3, 16, 6, 18, 31, 31, 29, 29, 4><<<GRIDT(29, 29, 4, 3), blk, 0, stream>>>(A, ow[1], ob[1], OFF);
    deform_conv<3, 16, 32, 31, 31, 29, 29, true><<<GRIDD(841), blk, 0, stream>>>(A, OFF, w[1], bi[1], Bb);
    // stage 3 (no relu)
    conv_tile<5, 32, 10, 50, 29, 29, 25, 25, 4><<<GRIDT(25, 25, 4, 5), blk, 0, stream>>>(Bb, ow[2], ob[2], OFF);
    deform_conv<5, 32, 16, 29, 29, 25, 25, false><<<GRIDD(625), blk, 0, stream>>>(Bb, OFF, w[2], bi[2], A);
    // stage 4
    conv_tile<7, 16, 14, 98, 25, 25, 19, 19, 4><<<GRIDT(19, 19, 4, 7), blk, 0, stream>>>(A, ow[3], ob[3], OFF);
    deform_conv<7, 16, 16, 25, 25, 19, 19, true><<<GRIDD(361), blk, 0, stream>>>(A, OFF, w[3], bi[3], Bb);
    // stage 5
    conv_tile<5, 16, 10, 50, 19, 19, 15, 15, 4><<<GRIDT(15, 15, 4, 5), blk, 0, stream>>>(Bb, ow[4], ob[4], OFF);
    deform_conv<5, 16, 8, 19, 19, 15, 15, true><<<GRIDD(225), blk, 0, stream>>>(Bb, OFF, w[4], bi[4], A);
    // stage 6
    conv_tile<3, 8, 6, 18, 15, 15, 13, 13, 4><<<GRIDT(13, 13, 4, 3), blk, 0, stream>>>(A, ow[5], ob[5], OFF);
    deform_conv<3, 8, 4, 15, 15, 13, 13, true><<<GRIDD(169), blk, 0, stream>>>(A, OFF, w[5], bi[5], Bb);

    // fc1: (512,676) -> (512,256), relu
    fc_kernel<<<dim3((B * 256 + 255) / 256), blk, 0, stream>>>(Bb, fc1w, fc1b, Z, B, 676, 256, 1);
    // fc2: (512,256) -> (512,10)
    fc_kernel<<<dim3((B * 10 + 255) / 256), blk, 0, stream>>>(Z, fc2w, fc2b, out, B, 256, 10, 0);

    #undef GRIDT
    #undef GRIDD
}

// Round 3
// 2243.184 us; speedup vs baseline: 1.2959x; 1.2704x over previous
//
#include <hip/hip_runtime.h>

typedef __attribute__((ext_vector_type(8))) short bf16x8;
typedef __attribute__((ext_vector_type(4))) float f32x4;
typedef unsigned short ushort_t;

__device__ inline ushort_t bf16_trunc(float f) { return (ushort_t)(__float_as_uint(f) >> 16); }
__device__ inline float bf16_to_f(ushort_t u) { return __uint_as_float(((unsigned int)u) << 16); }

// ---------------------------------------------------------------------------
// NCHW fp32 -> NHWC bf16 hi/lo planes. One thread per spatial position.
// ---------------------------------------------------------------------------
template<int CI, int HW>
__global__ __launch_bounds__(256)
void convert_nhwc(const float* __restrict__ x, ushort_t* __restrict__ hi,
                  ushort_t* __restrict__ lo, int Mtotal)
{
    const int m = blockIdx.x * 256 + threadIdx.x;
    if (m >= Mtotal) return;
    const int b = m / HW, pos = m - b * HW;
    const float* xp = x + (size_t)b * CI * HW + pos;
    ushort_t* hp = hi + (size_t)m * CI;
    ushort_t* lp = lo + (size_t)m * CI;
#pragma unroll
    for (int ci = 0; ci < CI; ++ci) {
        const float v = xp[(size_t)ci * HW];
        const ushort_t h = bf16_trunc(v);
        hp[ci] = h;
        lp[ci] = bf16_trunc(v - bf16_to_f(h));
    }
}

// ---------------------------------------------------------------------------
// Weight prep: OIHW fp32 -> Bmat bf16 [kk][n][ci] hi/lo, zero-padded in kk,n.
// ---------------------------------------------------------------------------
template<int CI, int KK, int KKPAD, int NPAD, int OC>
__global__ __launch_bounds__(256)
void wprep(const float* __restrict__ w, ushort_t* __restrict__ bhi, ushort_t* __restrict__ blo)
{
    const int idx = blockIdx.x * 256 + threadIdx.x;
    if (idx >= KKPAD * NPAD * CI) return;
    const int kk  = idx / (NPAD * CI);
    const int rem = idx - kk * (NPAD * CI);
    const int n   = rem / CI;
    const int ci  = rem - n * CI;
    const float v = (kk < KK && n < OC) ? w[((size_t)n * CI + ci) * KK + kk] : 0.f;
    const ushort_t h = bf16_trunc(v);
    bhi[idx] = h;
    blo[idx] = bf16_trunc(v - bf16_to_f(h));
}

// ---------------------------------------------------------------------------
// MFMA implicit-im2col conv (offset convs). fp32 via bf16 hi/lo split:
//   a*b ~= a_hi*b_hi + a_hi*b_lo + a_lo*b_hi   (error ~2^-16, fp32 accum)
// m = (b,y,x) over ALL H*W positions (invalid tail discarded at store) so the
// A operand of tap (ky,kx) is X_nhwc + (ky*W+kx)*CI -- purely linear.
// Each wave: 2 m-tiles x NT n-tiles of 16x16 accumulators, K=32 per mfma.
// ---------------------------------------------------------------------------
template<int CI, int K, int H, int W, int Ho, int Wo, int OC, int NT, int KSTEPS>
__global__ __launch_bounds__(256)
void conv_mfma(const ushort_t* __restrict__ Xhi, const ushort_t* __restrict__ Xlo,
               const ushort_t* __restrict__ Bhi, const ushort_t* __restrict__ Blo,
               const float* __restrict__ bias, float* __restrict__ out, int Mtotal)
{
    constexpr int NPAD = NT * 16;
    constexpr int HW   = H * W;
    constexpr int HoWo = Ho * Wo;

    const int lane = threadIdx.x & 63;
    const int wid  = threadIdx.x >> 6;
    const int col  = lane & 15;
    const int quad = lane >> 4;

    const int mBase  = blockIdx.x * 128 + wid * 32;   // 2 m-tiles: mBase, mBase+16
    const int mLane  = mBase + col;

    f32x4 acc[2][NT];
#pragma unroll
    for (int mt = 0; mt < 2; ++mt)
#pragma unroll
        for (int nt = 0; nt < NT; ++nt) acc[mt][nt] = (f32x4){0.f, 0.f, 0.f, 0.f};

    const int aBase = mLane * CI;            // element base for A (m-tile 0)
    const int bLane = col * CI;              // per-lane part of B address

#pragma unroll
    for (int ks = 0; ks < KSTEPS; ++ks) {
        const int k0  = ks * 32 + quad * 8;  // lane's starting k (quad-uniform)
        const int tap = k0 / CI;
        const int ci  = k0 - tap * CI;
        const int dkk = (tap / K) * W + (tap - (tap / K) * K);  // ky*W + kx

        bf16x8 a[2][2];
#pragma unroll
        for (int mt = 0; mt < 2; ++mt) {
            const int aoff = aBase + mt * 16 * CI + dkk * CI + ci;
            a[mt][0] = *(const bf16x8*)(Xhi + aoff);
            a[mt][1] = *(const bf16x8*)(Xlo + aoff);
        }
#pragma unroll
        for (int nt = 0; nt < NT; ++nt) {
            const int boff = tap * NPAD * CI + nt * 16 * CI + bLane + ci;
            const bf16x8 bh = *(const bf16x8*)(Bhi + boff);
            const bf16x8 bl = *(const bf16x8*)(Blo + boff);
#pragma unroll
            for (int mt = 0; mt < 2; ++mt) {
                acc[mt][nt] = __builtin_amdgcn_mfma_f32_16x16x32_bf16(a[mt][0], bh, acc[mt][nt], 0, 0, 0);
                acc[mt][nt] = __builtin_amdgcn_mfma_f32_16x16x32_bf16(a[mt][1], bh, acc[mt][nt], 0, 0, 0);
                acc[mt][nt] = __builtin_amdgcn_mfma_f32_16x16x32_bf16(a[mt][0], bl, acc[mt][nt], 0, 0, 0);
            }
        }
    }

    // epilogue: C/D layout col=lane&15 (n), row=quad*4+reg (m within tile)
#pragma unroll
    for (int mt = 0; mt < 2; ++mt) {
#pragma unroll
        for (int nt = 0; nt < NT; ++nt) {
            const int n = nt * 16 + col;
            if (n < OC) {
                const float bv = bias[n];
#pragma unroll
                for (int r = 0; r < 4; ++r) {
                    const int m = mBase + mt * 16 + quad * 4 + r;
                    if (m < Mtotal) {
                        const int b   = m / HW;
                        const int pos = m - b * HW;
                        const int y   = pos / W;
                        const int x   = pos - y * W;
                        if (y < Ho && x < Wo)
                            out[((size_t)b * OC + n) * HoWo + y * Wo + x] = acc[mt][nt][r] + bv;
                    }
                }
            }
        }
    }
}

// ---------------------------------------------------------------------------
// Register-tiled direct VALID conv (stages 1 and 6 only).
// ---------------------------------------------------------------------------
template<int K, int CI, int NOC, int OC, int H, int W, int Ho, int Wo, int PIX>
__global__ __launch_bounds__(256)
void conv_tile(const float* __restrict__ x, const float* __restrict__ w,
               const float* __restrict__ bias, float* __restrict__ out)
{
    constexpr int KK   = K * K;
    constexpr int HoWo = Ho * Wo;
    constexpr int WoG  = (Wo + PIX - 1) / PIX;
    constexpr int G    = Ho * WoG;
    constexpr int XV   = PIX + K - 1;

    const int oc0   = blockIdx.y * NOC;
    const int g_all = blockIdx.x * 256 + threadIdx.x;
    const int b     = g_all / G;
    const int g     = g_all - b * G;
    const int oy    = g / WoG;
    const int ox0   = (g - oy * WoG) * PIX;

    const float* xb = x + (b * CI) * (H * W) + oy * W + ox0;
    const float* wp = w + oc0 * (CI * KK);

    float acc[PIX][NOC];
#pragma unroll
    for (int p = 0; p < PIX; ++p)
#pragma unroll
        for (int j = 0; j < NOC; ++j) acc[p][j] = bias[oc0 + j];

    const int lim = W - 1 - ox0;

    for (int ci = 0; ci < CI; ++ci) {
        const float* xc = xb + ci * (H * W);
#pragma unroll
        for (int ky = 0; ky < K; ++ky) {
            float xv[XV];
#pragma unroll
            for (int i = 0; i < XV; ++i) {
                const int off = (i <= lim) ? i : lim;
                xv[i] = xc[ky * W + off];
            }
#pragma unroll
            for (int kx = 0; kx < K; ++kx) {
#pragma unroll
                for (int p = 0; p < PIX; ++p) {
                    const float v = xv[p + kx];
#pragma unroll
                    for (int j = 0; j < NOC; ++j)
                        acc[p][j] = fmaf(v, wp[j * (CI * KK) + ci * KK + ky * K + kx], acc[p][j]);
                }
            }
        }
    }

    float* op = out + (b * OC + oc0) * HoWo + oy * Wo + ox0;
#pragma unroll
    for (int p = 0; p < PIX; ++p) {
        if (ox0 + p < Wo) {
#pragma unroll
            for (int j = 0; j < NOC; ++j) op[j * HoWo + p] = acc[p][j];
        }
    }
}

// ---------------------------------------------------------------------------
// Deformable conv (unchanged).
// ---------------------------------------------------------------------------
template<int K, int CI, int CO, int H, int W, int Ho, int Wo, bool RELU>
__global__ __launch_bounds__(256)
void deform_conv(const float* __restrict__ x, const float* __restrict__ off,
                 const float* __restrict__ w, const float* __restrict__ bias,
                 float* __restrict__ out)
{
    constexpr int KK   = K * K;
    constexpr int HoWo = Ho * Wo;
    const int b = blockIdx.y;
    const int s = blockIdx.x * 256 + threadIdx.x;
    if (s >= HoWo) return;
    const int oy = s / Wo;
    const int ox = s - oy * Wo;

    const float* xb   = x + b * (CI * H * W);
    const float* offp = off + (b * 2 * KK) * HoWo + s;

    float acc[CO];
#pragma unroll
    for (int o = 0; o < CO; ++o) acc[o] = 0.f;

    for (int kk = 0; kk < KK; ++kk) {
        const float dy = offp[(2 * kk + 0) * HoWo];
        const float dx = offp[(2 * kk + 1) * HoWo];
        const float py = (float)(kk / K + oy) + dy;
        const float px = (float)(kk % K + ox) + dx;
        const float y0f = floorf(py), x0f = floorf(px);
        const float wy = py - y0f, wx = px - x0f;
        const int y0 = (int)y0f, x0 = (int)x0f;
        const int y1 = y0 + 1,   x1 = x0 + 1;

        const float m00 = (y0 >= 0 && y0 < H && x0 >= 0 && x0 < W) ? 1.f : 0.f;
        const float m01 = (y0 >= 0 && y0 < H && x1 >= 0 && x1 < W) ? 1.f : 0.f;
        const float m10 = (y1 >= 0 && y1 < H && x0 >= 0 && x0 < W) ? 1.f : 0.f;
        const float m11 = (y1 >= 0 && y1 < H && x1 >= 0 && x1 < W) ? 1.f : 0.f;

        const float w00 = (1.f - wy) * (1.f - wx) * m00;
        const float w01 = (1.f - wy) * wx         * m01;
        const float w10 = wy         * (1.f - wx) * m10;
        const float w11 = wy         * wx         * m11;

        const int y0c = min(max(y0, 0), H - 1), y1c = min(max(y1, 0), H - 1);
        const int x0c = min(max(x0, 0), W - 1), x1c = min(max(x1, 0), W - 1);
        const int i00 = y0c * W + x0c, i01 = y0c * W + x1c;
        const int i10 = y1c * W + x0c, i11 = y1c * W + x1c;

        for (int c = 0; c < CI; ++c) {
            const float* xc = xb + c * (H * W);
            float sv = xc[i00] * w00;
            sv = fmaf(xc[i01], w01, sv);
            sv = fmaf(xc[i10], w10, sv);
            sv = fmaf(xc[i11], w11, sv);
#pragma unroll
            for (int o = 0; o < CO; ++o)
                acc[o] = fmaf(sv, w[(o * CI + c) * KK + kk], acc[o]);
        }
    }

    float* op = out + (b * CO) * HoWo + s;
#pragma unroll
    for (int o = 0; o < CO; ++o) {
        float v = acc[o] + bias[o];
        if (RELU) v = fmaxf(v, 0.f);
        op[o * HoWo] = v;
    }
}

__global__ void fc_kernel(const float* __restrict__ h, const float* __restrict__ w,
                          const float* __restrict__ bias, float* __restrict__ out,
                          int B, int IN, int OUT, int relu)
{
    const int idx = blockIdx.x * blockDim.x + threadIdx.x;
    if (idx >= B * OUT) return;
    const int b = idx / OUT;
    const int j = idx - b * OUT;
    const float* hb = h + b * IN;
    const float* wj = w + j * IN;
    float acc = bias[j];
    for (int i = 0; i < IN; ++i) acc = fmaf(hb[i], wj[i], acc);
    if (relu) acc = fmaxf(acc, 0.f);
    out[idx] = acc;
}

// ---------------------------------------------------------------------------
extern "C" void kernel_launch(void* const* d_in, const int* in_sizes, int n_in,
                              void* d_out, int out_size, void* d_ws, size_t ws_size,
                              hipStream_t stream)
{
    const int B = 512;
    const float* x = (const float*)d_in[0];
    const float *ow[6], *ob[6], *w[6], *bi[6];
    for (int i = 0; i < 6; ++i) {
        ow[i] = (const float*)d_in[1 + 4 * i];
        ob[i] = (const float*)d_in[2 + 4 * i];
        w[i]  = (const float*)d_in[3 + 4 * i];
        bi[i] = (const float*)d_in[4 + 4 * i];
    }
    const float* fc1w = (const float*)d_in[25];
    const float* fc1b = (const float*)d_in[26];
    const float* fc2w = (const float*)d_in[27];
    const float* fc2b = (const float*)d_in[28];
    float* out = (float*)d_out;

    // workspace (floats): A | Bb | OFF | Z | WBhi | WBlo
    float* A   = (float*)d_ws;
    float* Bb  = A  + 14000000;
    float* OFF = Bb + 14000000;
    float* Z   = OFF + 18200000;
    float* WBf = Z + 200000;                // weight bf16 planes (hi, lo)
    ushort_t* WBhi = (ushort_t*)WBf;        // max 179200 ushort each
    ushort_t* WBlo = WBhi + 200000;

    const dim3 blk(256);
    #define GRIDT(Ho, Wo, PIX, NG) dim3((B * (Ho) * (((Wo) + (PIX) - 1) / (PIX)) + 255) / 256, (NG), 1)
    #define GRIDD(HoWo)            dim3(((HoWo) + 255) / 256, B)
    #define CEILDIV(a, b) (((a) + (b) - 1) / (b))

    // ---- stage 1 (conv_tile + deform), input x, out A ----
    conv_tile<3, 1, 6, 18, 33, 33, 31, 31, 4><<<GRIDT(31, 31, 4, 3), blk, 0, stream>>>(x, ow[0], ob[0], OFF);
    deform_conv<3, 1, 16, 33, 33, 31, 31, true><<<GRIDD(961), blk, 0, stream>>>(x, OFF, w[0], bi[0], A);

    // ---- stage 2: CI=16 K=3 31x31->29x29 OC=18 NT=2 KSTEPS=5 KKPAD=10 ----
    {
        const int M = B * 961;                      // 492032
        ushort_t* Xhi = (ushort_t*)Bb;              // Bb-slot free until deform2 writes
        ushort_t* Xlo = Xhi + (size_t)(M + 2048) * 16;
        convert_nhwc<16, 961><<<CEILDIV(M, 256), blk, 0, stream>>>(A, Xhi, Xlo, M);
        wprep<16, 9, 10, 32, 18><<<CEILDIV(10 * 32 * 16, 256), blk, 0, stream>>>(ow[1], WBhi, WBlo);
        conv_mfma<16, 3, 31, 31, 29, 29, 18, 2, 5><<<CEILDIV(M, 128), blk, 0, stream>>>(Xhi, Xlo, WBhi, WBlo, ob[1], OFF, M);
        deform_conv<3, 16, 32, 31, 31, 29, 29, true><<<GRIDD(841), blk, 0, stream>>>(A, OFF, w[1], bi[1], Bb);
    }
    // ---- stage 3: CI=32 K=5 29x29->25x25 OC=50 NT=4 KSTEPS=25 KKPAD=25 (no relu) ----
    {
        const int M = B * 841;                      // 430592
        ushort_t* Xhi = (ushort_t*)A;               // A-slot free until deform3 writes
        ushort_t* Xlo = Xhi + (size_t)(M + 2048) * 32;
        convert_nhwc<32, 841><<<CEILDIV(M, 256), blk, 0, stream>>>(Bb, Xhi, Xlo, M);
        wprep<32, 25, 25, 64, 50><<<CEILDIV(25 * 64 * 32, 256), blk, 0, stream>>>(ow[2], WBhi, WBlo);
        conv_mfma<32, 5, 29, 29, 25, 25, 50, 4, 25><<<CEILDIV(M, 128), blk, 0, stream>>>(Xhi, Xlo, WBhi, WBlo, ob[2], OFF, M);
        deform_conv<5, 32, 16, 29, 29, 25, 25, false><<<GRIDD(625), blk, 0, stream>>>(Bb, OFF, w[2], bi[2], A);
    }
    // ---- stage 4: CI=16 K=7 25x25->19x19 OC=98 NT=7 KSTEPS=25 KKPAD=50 ----
    {
        const int M = B * 625;                      // 320000
        ushort_t* Xhi = (ushort_t*)Bb;
        ushort_t* Xlo = Xhi + (size_t)(M + 2048) * 16;
        convert_nhwc<16, 625><<<CEILDIV(M, 256), blk, 0, stream>>>(A, Xhi, Xlo, M);
        wprep<16, 49, 50, 112, 98><<<CEILDIV(50 * 112 * 16, 256), blk, 0, stream>>>(ow[3], WBhi, WBlo);
        conv_mfma<16, 7, 25, 25, 19, 19, 98, 7, 25><<<CEILDIV(M, 128), blk, 0, stream>>>(Xhi, Xlo, WBhi, WBlo, ob[3], OFF, M);
        deform_conv<7, 16, 16, 25, 25, 19, 19, true><<<GRIDD(361), blk, 0, stream>>>(A, OFF, w[3], bi[3], Bb);
    }
    // ---- stage 5: CI=16 K=5 19x19->15x15 OC=50 NT=4 KSTEPS=13 KKPAD=26 ----
    {
        const int M = B * 361;                      // 184832
        ushort_t* Xhi = (ushort_t*)A;
        ushort_t* Xlo = Xhi + (size_t)(M + 2048) * 16;
        convert_nhwc<16, 361><<<CEILDIV(M, 256), blk, 0, stream>>>(Bb, Xhi, Xlo, M);
        wprep<16, 25, 26, 64, 50><<<CEILDIV(26 * 64 * 16, 256), blk, 0, stream>>>(ow[4], WBhi, WBlo);
        conv_mfma<16, 5, 19, 19, 15, 15, 50, 4, 13><<<CEILDIV(M, 128), blk, 0, stream>>>(Xhi, Xlo, WBhi, WBlo, ob[4], OFF, M);
        deform_conv<5, 16, 8, 19, 19, 15, 15, true><<<GRIDD(225), blk, 0, stream>>>(Bb, OFF, w[4], bi[4], A);
    }
    // ---- stage 6 (conv_tile + deform), input A, out Bb ----
    conv_tile<3, 8, 6, 18, 15, 15, 13, 13, 4><<<GRIDT(13, 13, 4, 3), blk, 0, stream>>>(A, ow[5], ob[5], OFF);
    deform_conv<3, 8, 4, 15, 15, 13, 13, true><<<GRIDD(169), blk, 0, stream>>>(A, OFF, w[5], bi[5], Bb);

    // ---- FC head ----
    fc_kernel<<<dim3(CEILDIV(B * 256, 256)), blk, 0, stream>>>(Bb, fc1w, fc1b, Z, B, 676, 256, 1);
    fc_kernel<<<dim3(CEILDIV(B * 10, 256)), blk, 0, stream>>>(Z, fc2w, fc2b, out, B, 256, 10, 0);

    #undef GRIDT
    #undef GRIDD
    #undef CEILDIV
}